// Round 11
// baseline (846.244 us; speedup 1.0000x reference)
//
#include <hip/hip_runtime.h>
#include <hip/hip_bf16.h>

typedef short short8 __attribute__((ext_vector_type(8)));
typedef float f32x4 __attribute__((ext_vector_type(4)));

#define DEV __device__ __forceinline__
#define AS1 __attribute__((address_space(1)))
#define AS3 __attribute__((address_space(3)))

// ---------------------------------------------------------------- async 16B global->LDS (GEMM)
DEV void async_load16(const void* g, void* l) {
    __builtin_amdgcn_global_load_lds((const AS1 unsigned int*)g, (AS3 unsigned int*)l, 16, 0, 0);
}

// ---------------------------------------------------------------- DPP 16-lane sum butterfly
template <int CTRL>
DEV float dpp_add16(float v) {
    int t = __builtin_amdgcn_update_dpp(0, __float_as_int(v), CTRL, 0xf, 0xf, true);
    return v + __int_as_float(t);
}
DEV float row_sum16(float v) {
    v = dpp_add16<0x128>(v);  // row_ror:8
    v = dpp_add16<0x124>(v);  // row_ror:4
    v = dpp_add16<0x122>(v);  // row_ror:2
    v = dpp_add16<0x121>(v);  // row_ror:1
    return v;
}

// ---------------------------------------------------------------- f32 -> bf16 cast (x)
__global__ __launch_bounds__(256) void cast_bf16_kernel(const float* __restrict__ in,
                                                        __hip_bfloat16* __restrict__ out, int n) {
    int i = (blockIdx.x * 256 + threadIdx.x) * 4;
    if (i < n) {
        float4 v = *(const float4*)&in[i];
        out[i + 0] = __float2bfloat16(v.x);
        out[i + 1] = __float2bfloat16(v.y);
        out[i + 2] = __float2bfloat16(v.z);
        out[i + 3] = __float2bfloat16(v.w);
    }
}

// ---------------------------------------------------------------- 6 weight casts in one launch
__global__ __launch_bounds__(256) void cast6_kernel(const float* __restrict__ s0, const float* __restrict__ s1,
                                                    const float* __restrict__ s2, const float* __restrict__ s3,
                                                    const float* __restrict__ s4, const float* __restrict__ s5,
                                                    __hip_bfloat16* __restrict__ dst) {
    const int sec = blockIdx.x >> 12;
    const int loc = blockIdx.x & 4095;
    const float* s = sec == 0 ? s0 : sec == 1 ? s1 : sec == 2 ? s2 : sec == 3 ? s3 : sec == 4 ? s4 : s5;
    const int i = (loc * 256 + threadIdx.x) * 4;
    float4 v = *(const float4*)&s[i];
    __hip_bfloat16* o = dst + (size_t)sec * 4194304 + i;
    o[0] = __float2bfloat16(v.x);
    o[1] = __float2bfloat16(v.y);
    o[2] = __float2bfloat16(v.z);
    o[3] = __float2bfloat16(v.w);
}

// ---------------------------------------------------------------- bf16 MFMA GEMM, C = A(M,K) * B(N,K)^T
// XCD-aware swizzle (nwg divisible by 8). EPI 0: plain f32 store.
// EPI 2: fused 5-section output (q|k|v|a|g), sigmoid+bias on sections 3 (bias1) and 4 (bias2).
template <int EPI>
__global__ __launch_bounds__(256) void gemm_nt(const short* __restrict__ A,
                                               const short* __restrict__ Bm,
                                               float* __restrict__ C,
                                               const float* __restrict__ bias1,
                                               const float* __restrict__ bias2,
                                               int M, int N, int K) {
    __shared__ short lda[128 * 32];
    __shared__ short ldb[128 * 32];
    const int tid  = threadIdx.x;
    const int lane = tid & 63;
    const int wave = tid >> 6;

    const int nbx = M >> 7;  // 32
    const int wg  = blockIdx.y * gridDim.x + blockIdx.x;
    const int nwg = gridDim.x * gridDim.y;
    const int cpx = nwg >> 3;
    const int swz = (wg & 7) * cpx + (wg >> 3);
    const int m0 = (swz & (nbx - 1)) * 128;
    const int n0 = (swz / nbx) * 128;

    const int wm = (wave >> 1) * 64;
    const int wn = (wave & 1) * 64;
    f32x4 acc[4][4] = {};

    const int sr = tid >> 2;
    const int sc = (tid & 3) * 8;
    const short* Ab  = A  + (size_t)(m0 + sr) * K + sc;
    const short* Ab2 = Ab + (size_t)64 * K;
    const short* Bb  = Bm + (size_t)(n0 + sr) * K + sc;
    const short* Bb2 = Bb + (size_t)64 * K;
    short* la  = &lda[tid * 8];
    short* la2 = &lda[(tid + 256) * 8];
    short* lb  = &ldb[tid * 8];
    short* lb2 = &ldb[(tid + 256) * 8];

    const int fk = (lane >> 4) * 8;
    const int fr = lane & 15;

    for (int k0 = 0; k0 < K; k0 += 32) {
        async_load16(Ab + k0,  la);
        async_load16(Ab2 + k0, la2);
        async_load16(Bb + k0,  lb);
        async_load16(Bb2 + k0, lb2);
        __syncthreads();
        short8 af[4], bfr[4];
#pragma unroll
        for (int i = 0; i < 4; i++) af[i]  = *(const short8*)&lda[(wm + i * 16 + fr) * 32 + fk];
#pragma unroll
        for (int j = 0; j < 4; j++) bfr[j] = *(const short8*)&ldb[(wn + j * 16 + fr) * 32 + fk];
#pragma unroll
        for (int i = 0; i < 4; i++)
#pragma unroll
            for (int j = 0; j < 4; j++)
                acc[i][j] = __builtin_amdgcn_mfma_f32_16x16x32_bf16(af[i], bfr[j], acc[i][j], 0, 0, 0);
        __syncthreads();
    }

    const int er = (lane >> 4) * 4;
    const int ec = lane & 15;
    bool sig = false;
    const float* bp = nullptr;
    if constexpr (EPI == 2) {
        sig = (n0 >= 6144);
        if (sig) bp = (n0 >= 8192) ? (bias2 + (n0 - 8192)) : (bias1 + (n0 - 6144));
    }
#pragma unroll
    for (int i = 0; i < 4; i++) {
        const int gr = m0 + wm + i * 16 + er;
#pragma unroll
        for (int j = 0; j < 4; j++) {
            const int gc = n0 + wn + j * 16 + ec;
            float bia = 0.f;
            if constexpr (EPI == 2) { if (sig) bia = bp[wn + j * 16 + ec]; }
#pragma unroll
            for (int r = 0; r < 4; r++) {
                float v = acc[i][j][r];
                if constexpr (EPI == 2) { if (sig) v = 1.f / (1.f + __expf(-(v + bia))); }
                C[(size_t)(gr + r) * N + gc] = v;
            }
        }
    }
}

// ---------------------------------------------------------------- l2norm over rows of 128 (fused layout)
__global__ __launch_bounds__(256) void l2norm_kernel(float* __restrict__ buf) {
    const int id   = blockIdx.x * 4 + (threadIdx.x >> 6);  // 0..131071
    const int lane = threadIdx.x & 63;
    const int t = id >> 5, rem = id & 31;
    float* p = &buf[(size_t)t * 10240 + (rem >> 4) * 2048 + (rem & 15) * 128 + lane * 2];
    float2 v = *(float2*)p;
    float s = v.x * v.x + v.y * v.y;
#pragma unroll
    for (int off = 1; off < 64; off <<= 1) s += __shfl_xor(s, off);
    const float inv = 1.f / fmaxf(sqrtf(s), 1e-12f);
    v.x *= inv; v.y *= inv;
    *(float2*)p = v;
}

// ---------------------------------------------------------------- beta = sigmoid(x @ Wb^T + bb), f32 exact
__global__ __launch_bounds__(256) void beta_kernel(const float* __restrict__ x,
                                                   const float* __restrict__ Wb,
                                                   const float* __restrict__ bb,
                                                   float* __restrict__ beta) {
    __shared__ float xs[16 * 132];
    const int tid = threadIdx.x;
    const float* xr = &x[(size_t)blockIdx.x * 2048];
#pragma unroll
    for (int i = tid; i < 512; i += 256) {
        float4 v = ((const float4*)xr)[i];
        const int j = i * 4;
        *(float4*)&xs[(j >> 7) * 132 + (j & 127)] = v;
    }
    __syncthreads();
    const int n = tid >> 4, ks = tid & 15;
    const float* w  = &Wb[(size_t)n * 2048 + ks * 128];
    const float* xx = &xs[ks * 132];
    float s = 0.f;
#pragma unroll 8
    for (int j = 0; j < 128; j++) s += xx[j] * w[j];
    s += __shfl_xor(s, 1); s += __shfl_xor(s, 2);
    s += __shfl_xor(s, 4); s += __shfl_xor(s, 8);
    if (ks == 0) beta[(size_t)blockIdx.x * 16 + n] = 1.f / (1.f + __expf(-(s + bb[n])));
}

// ---------------------------------------------------------------- sequential recurrence
// R9 body, re-partitioned for TLP: 512 blocks x 128 thr (2 waves of 4 rows each)
// -> 2048 waves = 2 waves/SIMD. Two independent chains per SIMD interleave, filling
// each other's dependency stalls (the R9 limiter). amdgpu_waves_per_eu(2,2) caps the
// VGPR budget at 256/wave so the 4-deep rotation (~140 VGPR) still allocates
// spill-free (R7's failure mode). bh = blockIdx&31 keeps XCD-local streams.
__global__ __launch_bounds__(128)
__attribute__((amdgpu_waves_per_eu(2, 2)))
void recurrence_kernel(
        const float* __restrict__ S0, const float* __restrict__ qall,
        const float* __restrict__ bet, __hip_bfloat16* __restrict__ o) {
    __shared__ __hip_bfloat16 lout[2][64][4];

    const int bh   = blockIdx.x & 31;   // XCD = bh % 8
    const int rb16 = blockIdx.x >> 5;   // 0..15
    const int b = bh >> 4, h = bh & 15;
    const int lane = threadIdx.x & 63;
    const int wave = threadIdx.x >> 6;  // 0..1
    const int r = lane >> 4;                // row within wave (0..3)
    const int c = lane & 15;                // col chunk (8 f32)
    const int i0 = rb16 * 8 + wave * 4;
    const int i = i0 + r;

    f32x4 S40, S41;
    {
        const float* s0 = &S0[((size_t)(bh * 128 + i)) * 128 + c * 8];
        S40 = *(const f32x4*)s0;
        S41 = *(const f32x4*)(s0 + 4);
    }

    const unsigned SB = 10240 * 4;         // bytes per t-step in fused buffer
    const float* rowb = qall + (size_t)(b * 2048) * 10240 + h * 128;
    const float* qbase = rowb;             // section 0
    const float* kbase = rowb + 2048;      // section 1
    const float* vbase = rowb + 4096;      // section 2
    const float* abase = rowb + 6144;      // section 3
    const float* gbase = rowb + 8192;      // section 4
    const float* bbase = bet + (size_t)(b * 2048) * 16 + h;
    char* ob = (char*)(o + ((size_t)(b * 2048) * 16 + h) * 128 + i0);

    unsigned voff_kq = (unsigned)(c * 32);  // c*8 floats * 4B
    unsigned voff_i  = (unsigned)(i * 4);
    unsigned voff_b  = 0;

    f32x4 kA0, kA1, qA0, qA1; float vA, aA, gA, bA;
    f32x4 kB0, kB1, qB0, qB1; float vB, aB, gB, bB;
    f32x4 kC0, kC1, qC0, qC1; float vC, aC, gC, bC;
    f32x4 kD0, kD1, qD0, qD1; float vD, aD, gD, bD;

#define ISSUE(SET)                                                              \
    asm volatile("global_load_dwordx4 %0, %2, %3\n\t"                           \
                 "global_load_dwordx4 %1, %2, %3 offset:16"                     \
                 : "=v"(k##SET##0), "=v"(k##SET##1)                             \
                 : "v"(voff_kq), "s"(kbase));                                   \
    asm volatile("global_load_dwordx4 %0, %2, %3\n\t"                           \
                 "global_load_dwordx4 %1, %2, %3 offset:16"                     \
                 : "=v"(q##SET##0), "=v"(q##SET##1)                             \
                 : "v"(voff_kq), "s"(qbase));                                   \
    asm volatile("global_load_dword %0, %1, %2"                                 \
                 : "=v"(v##SET) : "v"(voff_i), "s"(vbase));                     \
    asm volatile("global_load_dword %0, %1, %2"                                 \
                 : "=v"(a##SET) : "v"(voff_i), "s"(abase));                     \
    asm volatile("global_load_dword %0, %1, %2"                                 \
                 : "=v"(g##SET) : "v"(voff_i), "s"(gbase));                     \
    asm volatile("global_load_dword %0, %1, %2"                                 \
                 : "=v"(b##SET) : "v"(voff_b), "s"(bbase));

#define ADV() { voff_kq += SB; voff_i += SB; voff_b += 64; }

    // prologue: issue steps 0..3 into A..D
    ISSUE(A); ADV();
    ISSUE(B); ADV();
    ISSUE(C); ADV();
    ISSUE(D); ADV();

#define BODY(SLOT, SET)                                                   \
    {                                                                     \
        asm volatile("s_waitcnt vmcnt(24)");                              \
        asm volatile("" : "+v"(k##SET##0), "+v"(k##SET##1),               \
                          "+v"(q##SET##0), "+v"(q##SET##1),               \
                          "+v"(v##SET), "+v"(a##SET),                     \
                          "+v"(g##SET), "+v"(b##SET));                    \
        f32x4 ps = S40 * k##SET##0;                                       \
        ps = S41 * k##SET##1 + ps;                                        \
        float p = row_sum16((ps[0] + ps[1]) + (ps[2] + ps[3]));           \
        const float coef = b##SET * (v##SET - p);                         \
        S40 = a##SET * S40 + coef * k##SET##0;                            \
        S41 = a##SET * S41 + coef * k##SET##1;                            \
        f32x4 os = S40 * q##SET##0;                                       \
        os = S41 * q##SET##1 + os;                                        \
        float ov = row_sum16((os[0] + os[1]) + (os[2] + os[3]));          \
        if (c == 0) lout[wave][(SLOT)][r] = __float2bfloat16(ov * g##SET);\
        ISSUE(SET);                                                       \
        ADV();                                                            \
    }

    for (int tb = 0; tb < 2048; tb += 64) {
        for (int tt = 0; tt < 64; tt += 4) {
            BODY(tt,     A);
            BODY(tt + 1, B);
            BODY(tt + 2, C);
            BODY(tt + 3, D);
        }
        // flush 64 outputs: lane l -> step tb+l, 4 rows (8B)
        uint2 pk = *(const uint2*)&lout[wave][lane][0];
        *(uint2*)(ob + (size_t)(tb + lane) * 4096) = pk;
    }
#undef BODY
#undef ADV
#undef ISSUE
}

// ----------------------------------------------------------------
extern "C" void kernel_launch(void* const* d_in, const int* in_sizes, int n_in,
                              void* d_out, int out_size, void* d_ws, size_t ws_size,
                              hipStream_t stream) {
    const float* x  = (const float*)d_in[0];
    const float* S0 = (const float*)d_in[1];
    const float* Wq = (const float*)d_in[2];
    const float* Wk = (const float*)d_in[3];
    const float* Wv = (const float*)d_in[4];
    const float* Wa = (const float*)d_in[5];
    const float* ba = (const float*)d_in[6];
    const float* Wb = (const float*)d_in[7];
    const float* bb = (const float*)d_in[8];
    const float* Wg = (const float*)d_in[9];
    const float* bg = (const float*)d_in[10];
    const float* Wo = (const float*)d_in[11];
    float* out = (float*)d_out;

    const int M = 4096, K = 2048;
    const int NF = 10240;                       // fused projection width
    const size_t SLACK = 8 * (size_t)NF * 4;    // prefetch overrun slack

    size_t off = 0;
    auto alloc = [&](size_t bytes) {
        void* p = (char*)d_ws + off;
        off += (bytes + 255) & ~(size_t)255;
        return p;
    };
    short* x_bf  = (short*)alloc((size_t)M * K * 2);     // later reused as o_bf
    short* W_bf  = (short*)alloc((size_t)6 * K * K * 2); // Wq|Wk|Wv|Wa|Wg|Wo contiguous
    float* qall  = (float*)alloc((size_t)M * NF * 4 + SLACK);
    float* betab = (float*)alloc((size_t)M * 16 * 4 + 32768);

    // casts
    cast_bf16_kernel<<<dim3(M * K / 1024), dim3(256), 0, stream>>>(x, (__hip_bfloat16*)x_bf, M * K);
    cast6_kernel<<<dim3(6 * 4096), dim3(256), 0, stream>>>(Wq, Wk, Wv, Wa, Wg, Wo, (__hip_bfloat16*)W_bf);

    // fused 5-projection GEMM: [4096,2048] x [10240,2048]^T -> [4096,10240]
    gemm_nt<2><<<dim3(M / 128, NF / 128), dim3(256), 0, stream>>>(
        x_bf, W_bf, qall, ba, bg, M, NF, K);

    // l2norm q,k sections; beta
    l2norm_kernel<<<dim3(32768), dim3(256), 0, stream>>>(qall);
    beta_kernel<<<dim3(M), dim3(256), 0, stream>>>(x, Wb, bb, betab);

    // recurrence: writes o (bf16) over x_bf region (dead after fused GEMM)
    __hip_bfloat16* o_bf = (__hip_bfloat16*)x_bf;
    recurrence_kernel<<<dim3(512), dim3(128), 0, stream>>>(S0, qall, betab, o_bf);

    // out = (o*g) @ Wo^T   (Wo is section 5 of W_bf)
    gemm_nt<0><<<dim3(M / 128, K / 128), dim3(256), 0, stream>>>(
        (const short*)o_bf, W_bf + (size_t)5 * K * K, out, nullptr, nullptr, M, K, K);
}

// Round 14
// 740.118 us; speedup vs baseline: 1.1434x; 1.1434x over previous
//
#include <hip/hip_runtime.h>
#include <hip/hip_bf16.h>

typedef short short8 __attribute__((ext_vector_type(8)));
typedef float f32x4 __attribute__((ext_vector_type(4)));

#define DEV __device__ __forceinline__
#define AS1 __attribute__((address_space(1)))
#define AS3 __attribute__((address_space(3)))

// ---------------------------------------------------------------- async 16B global->LDS (GEMM)
DEV void async_load16(const void* g, void* l) {
    __builtin_amdgcn_global_load_lds((const AS1 unsigned int*)g, (AS3 unsigned int*)l, 16, 0, 0);
}

// ---------------------------------------------------------------- DPP 16-lane sum butterfly
template <int CTRL>
DEV float dpp_add16(float v) {
    int t = __builtin_amdgcn_update_dpp(0, __float_as_int(v), CTRL, 0xf, 0xf, true);
    return v + __int_as_float(t);
}
DEV float row_sum16(float v) {
    v = dpp_add16<0x128>(v);  // row_ror:8
    v = dpp_add16<0x124>(v);  // row_ror:4
    v = dpp_add16<0x122>(v);  // row_ror:2
    v = dpp_add16<0x121>(v);  // row_ror:1
    return v;
}

// ---------------------------------------------------------------- f32 -> bf16 cast (x)
__global__ __launch_bounds__(256) void cast_bf16_kernel(const float* __restrict__ in,
                                                        __hip_bfloat16* __restrict__ out, int n) {
    int i = (blockIdx.x * 256 + threadIdx.x) * 4;
    if (i < n) {
        float4 v = *(const float4*)&in[i];
        out[i + 0] = __float2bfloat16(v.x);
        out[i + 1] = __float2bfloat16(v.y);
        out[i + 2] = __float2bfloat16(v.z);
        out[i + 3] = __float2bfloat16(v.w);
    }
}

// ---------------------------------------------------------------- 6 weight casts in one launch
__global__ __launch_bounds__(256) void cast6_kernel(const float* __restrict__ s0, const float* __restrict__ s1,
                                                    const float* __restrict__ s2, const float* __restrict__ s3,
                                                    const float* __restrict__ s4, const float* __restrict__ s5,
                                                    __hip_bfloat16* __restrict__ dst) {
    const int sec = blockIdx.x >> 12;
    const int loc = blockIdx.x & 4095;
    const float* s = sec == 0 ? s0 : sec == 1 ? s1 : sec == 2 ? s2 : sec == 3 ? s3 : sec == 4 ? s4 : s5;
    const int i = (loc * 256 + threadIdx.x) * 4;
    float4 v = *(const float4*)&s[i];
    __hip_bfloat16* o = dst + (size_t)sec * 4194304 + i;
    o[0] = __float2bfloat16(v.x);
    o[1] = __float2bfloat16(v.y);
    o[2] = __float2bfloat16(v.z);
    o[3] = __float2bfloat16(v.w);
}

// ---------------------------------------------------------------- bf16 MFMA GEMM, C = A(M,K) * B(N,K)^T
// XCD-aware swizzle (nwg divisible by 8). EPI 0: plain f32 store.
// EPI 2: fused 5-section output (q|k|v|a|g):
//   - sections 0,1 (q,k; n0<4096): FUSED ROW L2NORM (tile is head-aligned, 128 wide
//     = one full head -> per-wave DPP partial + 1KB LDS cross-wave exchange)
//   - sections 3,4 (n0>=6144): sigmoid(+bias1/bias2)
template <int EPI>
__global__ __launch_bounds__(256) void gemm_nt(const short* __restrict__ A,
                                               const short* __restrict__ Bm,
                                               float* __restrict__ C,
                                               const float* __restrict__ bias1,
                                               const float* __restrict__ bias2,
                                               int M, int N, int K) {
    __shared__ short lda[128 * 32];
    __shared__ short ldb[128 * 32];
    __shared__ float lsum[2][128];
    const int tid  = threadIdx.x;
    const int lane = tid & 63;
    const int wave = tid >> 6;

    const int nbx = M >> 7;  // 32
    const int wg  = blockIdx.y * gridDim.x + blockIdx.x;
    const int nwg = gridDim.x * gridDim.y;
    const int cpx = nwg >> 3;
    const int swz = (wg & 7) * cpx + (wg >> 3);
    const int m0 = (swz & (nbx - 1)) * 128;
    const int n0 = (swz / nbx) * 128;

    const int wm = (wave >> 1) * 64;
    const int wn = (wave & 1) * 64;
    f32x4 acc[4][4] = {};

    const int sr = tid >> 2;
    const int sc = (tid & 3) * 8;
    const short* Ab  = A  + (size_t)(m0 + sr) * K + sc;
    const short* Ab2 = Ab + (size_t)64 * K;
    const short* Bb  = Bm + (size_t)(n0 + sr) * K + sc;
    const short* Bb2 = Bb + (size_t)64 * K;
    short* la  = &lda[tid * 8];
    short* la2 = &lda[(tid + 256) * 8];
    short* lb  = &ldb[tid * 8];
    short* lb2 = &ldb[(tid + 256) * 8];

    const int fk = (lane >> 4) * 8;
    const int fr = lane & 15;

    for (int k0 = 0; k0 < K; k0 += 32) {
        async_load16(Ab + k0,  la);
        async_load16(Ab2 + k0, la2);
        async_load16(Bb + k0,  lb);
        async_load16(Bb2 + k0, lb2);
        __syncthreads();
        short8 af[4], bfr[4];
#pragma unroll
        for (int i = 0; i < 4; i++) af[i]  = *(const short8*)&lda[(wm + i * 16 + fr) * 32 + fk];
#pragma unroll
        for (int j = 0; j < 4; j++) bfr[j] = *(const short8*)&ldb[(wn + j * 16 + fr) * 32 + fk];
#pragma unroll
        for (int i = 0; i < 4; i++)
#pragma unroll
            for (int j = 0; j < 4; j++)
                acc[i][j] = __builtin_amdgcn_mfma_f32_16x16x32_bf16(af[i], bfr[j], acc[i][j], 0, 0, 0);
        __syncthreads();
    }

    const int er = (lane >> 4) * 4;
    const int ec = lane & 15;

    if constexpr (EPI == 2) {
        if (n0 < 4096) {
            // fused row-l2norm: this 128-wide tile is exactly one head's D=128.
            // per-thread partial over its 4 j-cols, DPP-reduce the 16 ec lanes
            // (each DPP row = one output row), exchange the two wn-halves via LDS.
#pragma unroll
            for (int i = 0; i < 4; i++) {
                float p0 = acc[i][0][0]*acc[i][0][0] + acc[i][1][0]*acc[i][1][0]
                         + acc[i][2][0]*acc[i][2][0] + acc[i][3][0]*acc[i][3][0];
                float p1 = acc[i][0][1]*acc[i][0][1] + acc[i][1][1]*acc[i][1][1]
                         + acc[i][2][1]*acc[i][2][1] + acc[i][3][1]*acc[i][3][1];
                float p2 = acc[i][0][2]*acc[i][0][2] + acc[i][1][2]*acc[i][1][2]
                         + acc[i][2][2]*acc[i][2][2] + acc[i][3][2]*acc[i][3][2];
                float p3 = acc[i][0][3]*acc[i][0][3] + acc[i][1][3]*acc[i][1][3]
                         + acc[i][2][3]*acc[i][2][3] + acc[i][3][3]*acc[i][3][3];
                p0 = row_sum16(p0); p1 = row_sum16(p1);
                p2 = row_sum16(p2); p3 = row_sum16(p3);
                if (ec == 0) {
                    lsum[wave & 1][wm + i * 16 + er + 0] = p0;
                    lsum[wave & 1][wm + i * 16 + er + 1] = p1;
                    lsum[wave & 1][wm + i * 16 + er + 2] = p2;
                    lsum[wave & 1][wm + i * 16 + er + 3] = p3;
                }
            }
            __syncthreads();
#pragma unroll
            for (int i = 0; i < 4; i++)
#pragma unroll
                for (int r = 0; r < 4; r++) {
                    const int R = wm + i * 16 + er + r;
                    const float tot = lsum[0][R] + lsum[1][R];
                    const float inv = 1.f / fmaxf(sqrtf(tot), 1e-12f);
#pragma unroll
                    for (int j = 0; j < 4; j++) acc[i][j][r] *= inv;
                }
        }
    }

    bool sig = false;
    const float* bp = nullptr;
    if constexpr (EPI == 2) {
        sig = (n0 >= 6144);
        if (sig) bp = (n0 >= 8192) ? (bias2 + (n0 - 8192)) : (bias1 + (n0 - 6144));
    }
#pragma unroll
    for (int i = 0; i < 4; i++) {
        const int gr = m0 + wm + i * 16 + er;
#pragma unroll
        for (int j = 0; j < 4; j++) {
            const int gc = n0 + wn + j * 16 + ec;
            float bia = 0.f;
            if constexpr (EPI == 2) { if (sig) bia = bp[wn + j * 16 + ec]; }
#pragma unroll
            for (int r = 0; r < 4; r++) {
                float v = acc[i][j][r];
                if constexpr (EPI == 2) { if (sig) v = 1.f / (1.f + __expf(-(v + bia))); }
                C[(size_t)(gr + r) * N + gc] = v;
            }
        }
    }
}

// ---------------------------------------------------------------- beta = sigmoid(x @ Wb^T + bb), f32 exact
__global__ __launch_bounds__(256) void beta_kernel(const float* __restrict__ x,
                                                   const float* __restrict__ Wb,
                                                   const float* __restrict__ bb,
                                                   float* __restrict__ beta) {
    __shared__ float xs[16 * 132];
    const int tid = threadIdx.x;
    const float* xr = &x[(size_t)blockIdx.x * 2048];
#pragma unroll
    for (int i = tid; i < 512; i += 256) {
        float4 v = ((const float4*)xr)[i];
        const int j = i * 4;
        *(float4*)&xs[(j >> 7) * 132 + (j & 127)] = v;
    }
    __syncthreads();
    const int n = tid >> 4, ks = tid & 15;
    const float* w  = &Wb[(size_t)n * 2048 + ks * 128];
    const float* xx = &xs[ks * 132];
    float s = 0.f;
#pragma unroll 8
    for (int j = 0; j < 128; j++) s += xx[j] * w[j];
    s += __shfl_xor(s, 1); s += __shfl_xor(s, 2);
    s += __shfl_xor(s, 4); s += __shfl_xor(s, 8);
    if (ks == 0) beta[(size_t)blockIdx.x * 16 + n] = 1.f / (1.f + __expf(-(s + bb[n])));
}

// ---------------------------------------------------------------- sequential recurrence (R9-proven)
// 256 blocks x 4 waves, wave = 4 rows x 16 lanes, 8 state f32/lane, XCD-local bh.
// 4-deep asm-volatile register rotation (VGPR 132, spill-free at waves_per_eu(1,1)),
// counted s_waitcnt vmcnt(24) + dataflow register binding (no sched_barrier wall).
// Streams in fused [4096][10240] buffer: q=0,k=1,v=2,a=3,g=4 sections.
__global__ __launch_bounds__(256)
__attribute__((amdgpu_waves_per_eu(1, 1)))
void recurrence_kernel(
        const float* __restrict__ S0, const float* __restrict__ qall,
        const float* __restrict__ bet, __hip_bfloat16* __restrict__ o) {
    __shared__ __hip_bfloat16 lout[4][64][4];

    const int bh  = blockIdx.x & 31;   // XCD = bh % 8
    const int rb8 = blockIdx.x >> 5;   // 0..7
    const int b = bh >> 4, h = bh & 15;
    const int lane = threadIdx.x & 63;
    const int wave = threadIdx.x >> 6;
    const int r = lane >> 4;               // row within wave (0..3)
    const int c = lane & 15;               // col chunk (8 f32)
    const int i0 = rb8 * 16 + wave * 4;
    const int i = i0 + r;

    f32x4 S40, S41;
    {
        const float* s0 = &S0[((size_t)(bh * 128 + i)) * 128 + c * 8];
        S40 = *(const f32x4*)s0;
        S41 = *(const f32x4*)(s0 + 4);
    }

    const unsigned SB = 10240 * 4;         // bytes per t-step in fused buffer
    const float* rowb = qall + (size_t)(b * 2048) * 10240 + h * 128;
    const float* qbase = rowb;             // section 0
    const float* kbase = rowb + 2048;      // section 1
    const float* vbase = rowb + 4096;      // section 2
    const float* abase = rowb + 6144;      // section 3
    const float* gbase = rowb + 8192;      // section 4
    const float* bbase = bet + (size_t)(b * 2048) * 16 + h;
    char* ob = (char*)(o + ((size_t)(b * 2048) * 16 + h) * 128 + i0);

    unsigned voff_kq = (unsigned)(c * 32);  // c*8 floats * 4B
    unsigned voff_i  = (unsigned)(i * 4);
    unsigned voff_b  = 0;

    f32x4 kA0, kA1, qA0, qA1; float vA, aA, gA, bA;
    f32x4 kB0, kB1, qB0, qB1; float vB, aB, gB, bB;
    f32x4 kC0, kC1, qC0, qC1; float vC, aC, gC, bC;
    f32x4 kD0, kD1, qD0, qD1; float vD, aD, gD, bD;

#define ISSUE(SET)                                                              \
    asm volatile("global_load_dwordx4 %0, %2, %3\n\t"                           \
                 "global_load_dwordx4 %1, %2, %3 offset:16"                     \
                 : "=v"(k##SET##0), "=v"(k##SET##1)                             \
                 : "v"(voff_kq), "s"(kbase));                                   \
    asm volatile("global_load_dwordx4 %0, %2, %3\n\t"                           \
                 "global_load_dwordx4 %1, %2, %3 offset:16"                     \
                 : "=v"(q##SET##0), "=v"(q##SET##1)                             \
                 : "v"(voff_kq), "s"(qbase));                                   \
    asm volatile("global_load_dword %0, %1, %2"                                 \
                 : "=v"(v##SET) : "v"(voff_i), "s"(vbase));                     \
    asm volatile("global_load_dword %0, %1, %2"                                 \
                 : "=v"(a##SET) : "v"(voff_i), "s"(abase));                     \
    asm volatile("global_load_dword %0, %1, %2"                                 \
                 : "=v"(g##SET) : "v"(voff_i), "s"(gbase));                     \
    asm volatile("global_load_dword %0, %1, %2"                                 \
                 : "=v"(b##SET) : "v"(voff_b), "s"(bbase));

#define ADV() { voff_kq += SB; voff_i += SB; voff_b += 64; }

    // prologue: issue steps 0..3 into A..D
    ISSUE(A); ADV();
    ISSUE(B); ADV();
    ISSUE(C); ADV();
    ISSUE(D); ADV();

// counted wait for t's loads (24 newer outstanding), dataflow-bind the arrived set,
// compute t, buffer output in LDS ring, issue L(t+4) into the consumed set.
#define BODY(SLOT, SET)                                                   \
    {                                                                     \
        asm volatile("s_waitcnt vmcnt(24)");                              \
        asm volatile("" : "+v"(k##SET##0), "+v"(k##SET##1),               \
                          "+v"(q##SET##0), "+v"(q##SET##1),               \
                          "+v"(v##SET), "+v"(a##SET),                     \
                          "+v"(g##SET), "+v"(b##SET));                    \
        f32x4 ps = S40 * k##SET##0;                                       \
        ps = S41 * k##SET##1 + ps;                                        \
        float p = row_sum16((ps[0] + ps[1]) + (ps[2] + ps[3]));           \
        const float coef = b##SET * (v##SET - p);                         \
        S40 = a##SET * S40 + coef * k##SET##0;                            \
        S41 = a##SET * S41 + coef * k##SET##1;                            \
        f32x4 os = S40 * q##SET##0;                                       \
        os = S41 * q##SET##1 + os;                                        \
        float ov = row_sum16((os[0] + os[1]) + (os[2] + os[3]));          \
        if (c == 0) lout[wave][(SLOT)][r] = __float2bfloat16(ov * g##SET);\
        ISSUE(SET);                                                       \
        ADV();                                                            \
    }

    for (int tb = 0; tb < 2048; tb += 64) {
        for (int tt = 0; tt < 64; tt += 4) {
            BODY(tt,     A);
            BODY(tt + 1, B);
            BODY(tt + 2, C);
            BODY(tt + 3, D);
        }
        // flush 64 outputs: lane l -> step tb+l, 4 rows (8B)
        uint2 pk = *(const uint2*)&lout[wave][lane][0];
        *(uint2*)(ob + (size_t)(tb + lane) * 4096) = pk;
    }
#undef BODY
#undef ADV
#undef ISSUE
}

// ----------------------------------------------------------------
extern "C" void kernel_launch(void* const* d_in, const int* in_sizes, int n_in,
                              void* d_out, int out_size, void* d_ws, size_t ws_size,
                              hipStream_t stream) {
    const float* x  = (const float*)d_in[0];
    const float* S0 = (const float*)d_in[1];
    const float* Wq = (const float*)d_in[2];
    const float* Wk = (const float*)d_in[3];
    const float* Wv = (const float*)d_in[4];
    const float* Wa = (const float*)d_in[5];
    const float* ba = (const float*)d_in[6];
    const float* Wb = (const float*)d_in[7];
    const float* bb = (const float*)d_in[8];
    const float* Wg = (const float*)d_in[9];
    const float* bg = (const float*)d_in[10];
    const float* Wo = (const float*)d_in[11];
    float* out = (float*)d_out;

    const int M = 4096, K = 2048;
    const int NF = 10240;                        // fused projection width
    const size_t SLACK = 16 * (size_t)NF * 4;    // prefetch overrun slack

    size_t off = 0;
    auto alloc = [&](size_t bytes) {
        void* p = (char*)d_ws + off;
        off += (bytes + 255) & ~(size_t)255;
        return p;
    };
    short* x_bf  = (short*)alloc((size_t)M * K * 2);     // later reused as o_bf
    short* W_bf  = (short*)alloc((size_t)6 * K * K * 2); // Wq|Wk|Wv|Wa|Wg|Wo contiguous
    float* qall  = (float*)alloc((size_t)M * NF * 4 + SLACK);
    float* betab = (float*)alloc((size_t)M * 16 * 4 + 65536);

    // casts
    cast_bf16_kernel<<<dim3(M * K / 1024), dim3(256), 0, stream>>>(x, (__hip_bfloat16*)x_bf, M * K);
    cast6_kernel<<<dim3(6 * 4096), dim3(256), 0, stream>>>(Wq, Wk, Wv, Wa, Wg, Wo, (__hip_bfloat16*)W_bf);

    // fused 5-projection GEMM with fused l2norm (q,k) and sigmoid (a,g) epilogues
    gemm_nt<2><<<dim3(M / 128, NF / 128), dim3(256), 0, stream>>>(
        x_bf, W_bf, qall, ba, bg, M, NF, K);

    // beta (f32 exact)
    beta_kernel<<<dim3(M), dim3(256), 0, stream>>>(x, Wb, bb, betab);

    // recurrence: writes o (bf16) over x_bf region (dead after fused GEMM)
    __hip_bfloat16* o_bf = (__hip_bfloat16*)x_bf;
    recurrence_kernel<<<dim3(256), dim3(256), 0, stream>>>(S0, qall, betab, o_bf);

    // out = (o*g) @ Wo^T   (Wo is section 5 of W_bf)
    gemm_nt<0><<<dim3(M / 128, K / 128), dim3(256), 0, stream>>>(
        (const short*)o_bf, W_bf + (size_t)5 * K * K, out, nullptr, nullptr, M, K, K);
}

// Round 15
// 651.235 us; speedup vs baseline: 1.2994x; 1.1365x over previous
//
#include <hip/hip_runtime.h>
#include <hip/hip_bf16.h>

typedef short short8 __attribute__((ext_vector_type(8)));
typedef float f32x4 __attribute__((ext_vector_type(4)));

#define DEV __device__ __forceinline__
#define AS1 __attribute__((address_space(1)))
#define AS3 __attribute__((address_space(3)))

// ---------------------------------------------------------------- async 16B global->LDS
DEV void async_load16(const void* g, void* l) {
    __builtin_amdgcn_global_load_lds((const AS1 unsigned int*)g, (AS3 unsigned int*)l, 16, 0, 0);
}

// ---------------------------------------------------------------- DPP 16-lane sum butterfly
template <int CTRL>
DEV float dpp_add16(float v) {
    int t = __builtin_amdgcn_update_dpp(0, __float_as_int(v), CTRL, 0xf, 0xf, true);
    return v + __int_as_float(t);
}
DEV float row_sum16(float v) {
    v = dpp_add16<0x128>(v);  // row_ror:8
    v = dpp_add16<0x124>(v);  // row_ror:4
    v = dpp_add16<0x122>(v);  // row_ror:2
    v = dpp_add16<0x121>(v);  // row_ror:1
    return v;
}

// ---------------------------------------------------------------- f32 -> bf16 cast (x)
__global__ __launch_bounds__(256) void cast_bf16_kernel(const float* __restrict__ in,
                                                        __hip_bfloat16* __restrict__ out, int n) {
    int i = (blockIdx.x * 256 + threadIdx.x) * 4;
    if (i < n) {
        float4 v = *(const float4*)&in[i];
        out[i + 0] = __float2bfloat16(v.x);
        out[i + 1] = __float2bfloat16(v.y);
        out[i + 2] = __float2bfloat16(v.z);
        out[i + 3] = __float2bfloat16(v.w);
    }
}

// ---------------------------------------------------------------- 6 weight casts in one launch
__global__ __launch_bounds__(256) void cast6_kernel(const float* __restrict__ s0, const float* __restrict__ s1,
                                                    const float* __restrict__ s2, const float* __restrict__ s3,
                                                    const float* __restrict__ s4, const float* __restrict__ s5,
                                                    __hip_bfloat16* __restrict__ dst) {
    const int sec = blockIdx.x >> 12;
    const int loc = blockIdx.x & 4095;
    const float* s = sec == 0 ? s0 : sec == 1 ? s1 : sec == 2 ? s2 : sec == 3 ? s3 : sec == 4 ? s4 : s5;
    const int i = (loc * 256 + threadIdx.x) * 4;
    float4 v = *(const float4*)&s[i];
    __hip_bfloat16* o = dst + (size_t)sec * 4194304 + i;
    o[0] = __float2bfloat16(v.x);
    o[1] = __float2bfloat16(v.y);
    o[2] = __float2bfloat16(v.z);
    o[3] = __float2bfloat16(v.w);
}

// ---------------------------------------------------------------- 128^2 m97-style GEMM (out proj only)
__global__ __launch_bounds__(256) void gemm_nt(const short* __restrict__ A,
                                               const short* __restrict__ Bm,
                                               float* __restrict__ C,
                                               int M, int N, int K) {
    __shared__ short lda[128 * 32];
    __shared__ short ldb[128 * 32];
    const int tid  = threadIdx.x;
    const int lane = tid & 63;
    const int wave = tid >> 6;

    const int nbx = M >> 7;
    const int wg  = blockIdx.y * gridDim.x + blockIdx.x;
    const int nwg = gridDim.x * gridDim.y;
    const int cpx = nwg >> 3;
    const int swz = (wg & 7) * cpx + (wg >> 3);
    const int m0 = (swz & (nbx - 1)) * 128;
    const int n0 = (swz / nbx) * 128;

    const int wm = (wave >> 1) * 64;
    const int wn = (wave & 1) * 64;
    f32x4 acc[4][4] = {};

    const int sr = tid >> 2;
    const int sc = (tid & 3) * 8;
    const short* Ab  = A  + (size_t)(m0 + sr) * K + sc;
    const short* Ab2 = Ab + (size_t)64 * K;
    const short* Bb  = Bm + (size_t)(n0 + sr) * K + sc;
    const short* Bb2 = Bb + (size_t)64 * K;
    short* la  = &lda[tid * 8];
    short* la2 = &lda[(tid + 256) * 8];
    short* lb  = &ldb[tid * 8];
    short* lb2 = &ldb[(tid + 256) * 8];

    const int fk = (lane >> 4) * 8;
    const int fr = lane & 15;

    for (int k0 = 0; k0 < K; k0 += 32) {
        async_load16(Ab + k0,  la);
        async_load16(Ab2 + k0, la2);
        async_load16(Bb + k0,  lb);
        async_load16(Bb2 + k0, lb2);
        __syncthreads();
        short8 af[4], bfr[4];
#pragma unroll
        for (int i = 0; i < 4; i++) af[i]  = *(const short8*)&lda[(wm + i * 16 + fr) * 32 + fk];
#pragma unroll
        for (int j = 0; j < 4; j++) bfr[j] = *(const short8*)&ldb[(wn + j * 16 + fr) * 32 + fk];
#pragma unroll
        for (int i = 0; i < 4; i++)
#pragma unroll
            for (int j = 0; j < 4; j++)
                acc[i][j] = __builtin_amdgcn_mfma_f32_16x16x32_bf16(af[i], bfr[j], acc[i][j], 0, 0, 0);
        __syncthreads();
    }

    const int er = (lane >> 4) * 4;
    const int ec = lane & 15;
#pragma unroll
    for (int i = 0; i < 4; i++) {
        const int gr = m0 + wm + i * 16 + er;
#pragma unroll
        for (int j = 0; j < 4; j++) {
            const int gc = n0 + wn + j * 16 + ec;
#pragma unroll
            for (int r = 0; r < 4; r++)
                C[(size_t)(gr + r) * N + gc] = acc[i][j][r];
        }
    }
}

// ---------------------------------------------------------------- 256^2 8-phase GEMM (m201 template)
// C = A(M,K) x B(N,K)^T, fused epilogues by output-column section:
//   cols < 4096: row-l2norm (q,k) | 4096..6143: plain (v) | >=6144: sigmoid+bias (a,g)
// Geometry: BM=BN=256, BK=64, 512 thr (8 waves, 2Mx4N), per-wave out 128x64.
// LDS 128 KiB = 16 regions of 16KB: region = (matrix, dbuf, khalf) -> [256 rows][32 k] bf16.
// Swizzle: kbyte ^= ((row>>1)&3)<<4 (inverse-swizzled global source + swizzled ds_read).
// Per K-tile 4 phases (khalf x Nhalf); each phase stages ONE region (the one consumed
// the previous phase); vmcnt(6) once per K-tile => tile T fully landed before use.
__global__ __launch_bounds__(512, 2) void gemm256_fused(
        const short* __restrict__ A, const short* __restrict__ Bm,
        float* __restrict__ C, const float* __restrict__ bias1,
        const float* __restrict__ bias2, int M, int N, int K) {
    __shared__ short lds_s[65536];  // 131072 B

    const int tid  = threadIdx.x;
    const int lane = tid & 63;
    const int w    = tid >> 6;       // wave 0..7
    const int wave_m = w >> 2;       // 0..1
    const int wave_n = w & 3;        // 0..3
    const int fr  = lane & 15;
    const int fk2 = (lane >> 4) * 16;  // frag k-byte
    const int er  = (lane >> 4) * 4;
    const int ec  = lane & 15;

    // XCD swizzle (nwg % 8 == 0)
    const int nbx = M >> 8;          // M/256
    const int wg  = blockIdx.x;
    const int nwg = gridDim.x;
    const int cpx = nwg >> 3;
    const int swz = (wg & 7) * cpx + (wg >> 3);
    const int m0 = (swz & (nbx - 1)) * 256;
    const int n0 = (swz / nbx) * 256;

    const int Kb = K * 2;            // row bytes

    f32x4 acc[8][4] = {};

    // region byte offsets
#define AREG(d, kh) (((d) * 2 + (kh)) << 14)
#define BREG(d, kh) (65536 + (((d) * 2 + (kh)) << 14))

    // stage one region (256 rows x 32 k bf16 = 16KB): 2 gloads/thread.
    const int sr0 = w * 32 + (lane >> 2);
    const int sr1 = sr0 + 16;
    const int kbl = (lane & 3) * 16;
    auto STAGE = [&](const short* mat, int rc0, int tkoff, int region) {
        const char* g0 = (const char*)mat + (size_t)(rc0 + sr0) * Kb + tkoff + (kbl ^ (((sr0 >> 1) & 3) << 4));
        const char* g1 = (const char*)mat + (size_t)(rc0 + sr1) * Kb + tkoff + (kbl ^ (((sr1 >> 1) & 3) << 4));
        async_load16(g0, &lds_s[(region + w * 2048) >> 1]);
        async_load16(g1, &lds_s[(region + w * 2048 + 1024) >> 1]);
    };
    auto RDA = [&](int region, int i) -> short8 {
        const int ra = wave_m * 128 + i * 16 + fr;
        return *(const short8*)&lds_s[(region + ra * 64 + (fk2 ^ (((ra >> 1) & 3) << 4))) >> 1];
    };
    auto RDB = [&](int region, int j) -> short8 {
        const int cl = wave_n * 64 + j * 16 + fr;
        return *(const short8*)&lds_s[(region + cl * 64 + (fk2 ^ (((cl >> 1) & 3) << 4))) >> 1];
    };

    // prologue: stage tiles 0 and 1 fully (16 loads/thread), drain, barrier
    STAGE(A,  m0, 0,   AREG(0, 0));  STAGE(A,  m0, 64,  AREG(0, 1));
    STAGE(Bm, n0, 0,   BREG(0, 0));  STAGE(Bm, n0, 64,  BREG(0, 1));
    STAGE(A,  m0, 128, AREG(1, 0));  STAGE(A,  m0, 192, AREG(1, 1));
    STAGE(Bm, n0, 128, BREG(1, 0));  STAGE(Bm, n0, 192, BREG(1, 1));
    asm volatile("s_waitcnt vmcnt(0)" ::: "memory");
    __builtin_amdgcn_s_barrier();
    __builtin_amdgcn_sched_barrier(0);

    short8 af[8], b0, b1;
    const int NT = K >> 6;  // 32

#define MFMA8(JA, JB)                                                            \
    __builtin_amdgcn_s_setprio(1);                                               \
    _Pragma("unroll") for (int i = 0; i < 8; i++)                                \
        acc[i][JA] = __builtin_amdgcn_mfma_f32_16x16x32_bf16(af[i], b0, acc[i][JA], 0, 0, 0); \
    _Pragma("unroll") for (int i = 0; i < 8; i++)                                \
        acc[i][JB] = __builtin_amdgcn_mfma_f32_16x16x32_bf16(af[i], b1, acc[i][JB], 0, 0, 0); \
    __builtin_amdgcn_s_setprio(0);

#define ENDPH()                                                                  \
    __builtin_amdgcn_s_barrier();                                                \
    __builtin_amdgcn_sched_barrier(0);

#define KTILE(D, T)                                                              \
    {                                                                            \
        /* phase 0: kh0, nh0; stage B-k1(T+1) */                                 \
        _Pragma("unroll") for (int i = 0; i < 8; i++) af[i] = RDA(AREG(D, 0), i);\
        b0 = RDB(BREG(D, 0), 0); b1 = RDB(BREG(D, 0), 1);                        \
        STAGE(Bm, n0, ((T) + 1) * 128 + 64, BREG(D ^ 1, 1));                     \
        MFMA8(0, 1)                                                              \
        ENDPH()                                                                  \
        /* phase 1: kh0, nh1; stage A-k0(T+2) */                                 \
        b0 = RDB(BREG(D, 0), 2); b1 = RDB(BREG(D, 0), 3);                        \
        STAGE(A, m0, ((T) + 2) * 128, AREG(D, 0));                               \
        MFMA8(2, 3)                                                              \
        ENDPH()                                                                  \
        /* phase 2: kh1, nh0; stage B-k0(T+2) */                                 \
        _Pragma("unroll") for (int i = 0; i < 8; i++) af[i] = RDA(AREG(D, 1), i);\
        b0 = RDB(BREG(D, 1), 0); b1 = RDB(BREG(D, 1), 1);                        \
        STAGE(Bm, n0, ((T) + 2) * 128, BREG(D, 0));                              \
        MFMA8(0, 1)                                                              \
        ENDPH()                                                                  \
        /* phase 3: kh1, nh1; stage A-k1(T+2); vmcnt(6) */                       \
        b0 = RDB(BREG(D, 1), 2); b1 = RDB(BREG(D, 1), 3);                        \
        STAGE(A, m0, ((T) + 2) * 128 + 64, AREG(D, 1));                          \
        MFMA8(2, 3)                                                              \
        asm volatile("s_waitcnt vmcnt(6)" ::: "memory");                         \
        ENDPH()                                                                  \
    }

    for (int T = 0; T < NT; T += 2) {
        KTILE(0, T)
        KTILE(1, T + 1)
    }
#undef KTILE
#undef ENDPH
#undef MFMA8

    // ---------------- epilogue
    const bool isqk = (n0 < 4096);
    if (isqk) {
        __syncthreads();  // drain in-flight DMA + barrier before LDS reuse
        float* lsum = (float*)lds_s;   // [4][256]
#pragma unroll
        for (int i = 0; i < 8; i++) {
            float p[4];
#pragma unroll
            for (int r = 0; r < 4; r++) {
                float s = acc[i][0][r] * acc[i][0][r] + acc[i][1][r] * acc[i][1][r]
                        + acc[i][2][r] * acc[i][2][r] + acc[i][3][r] * acc[i][3][r];
                p[r] = row_sum16(s);
            }
            if (ec == 0) {
                const int R = wave_m * 128 + i * 16 + er;
                lsum[wave_n * 256 + R + 0] = p[0];
                lsum[wave_n * 256 + R + 1] = p[1];
                lsum[wave_n * 256 + R + 2] = p[2];
                lsum[wave_n * 256 + R + 3] = p[3];
            }
        }
        __syncthreads();
        const int h0 = (wave_n & 2);  // head-pair base (0 or 2)
#pragma unroll
        for (int i = 0; i < 8; i++)
#pragma unroll
            for (int r = 0; r < 4; r++) {
                const int R = wave_m * 128 + i * 16 + er + r;
                const float tot = lsum[h0 * 256 + R] + lsum[(h0 + 1) * 256 + R];
                const float inv = 1.f / fmaxf(sqrtf(tot), 1e-12f);
#pragma unroll
                for (int j = 0; j < 4; j++) acc[i][j][r] *= inv;
            }
    }

    const bool sig = (n0 >= 6144);
    const float* bp = nullptr;
    if (sig) bp = (n0 >= 8192) ? (bias2 + (n0 - 8192)) : (bias1 + (n0 - 6144));

#pragma unroll
    for (int i = 0; i < 8; i++) {
        const int gr = m0 + wave_m * 128 + i * 16 + er;
#pragma unroll
        for (int j = 0; j < 4; j++) {
            const int gc = n0 + wave_n * 64 + j * 16 + ec;
            float bia = 0.f;
            if (sig) bia = bp[wave_n * 64 + j * 16 + ec];
#pragma unroll
            for (int r = 0; r < 4; r++) {
                float v = acc[i][j][r];
                if (sig) v = 1.f / (1.f + __expf(-(v + bia)));
                C[(size_t)(gr + r) * N + gc] = v;
            }
        }
    }
    asm volatile("s_waitcnt vmcnt(0)" ::: "memory");  // drain tail DMAs before endpgm
}

// ---------------------------------------------------------------- beta = sigmoid(x @ Wb^T + bb), f32 exact
__global__ __launch_bounds__(256) void beta_kernel(const float* __restrict__ x,
                                                   const float* __restrict__ Wb,
                                                   const float* __restrict__ bb,
                                                   float* __restrict__ beta) {
    __shared__ float xs[16 * 132];
    const int tid = threadIdx.x;
    const float* xr = &x[(size_t)blockIdx.x * 2048];
#pragma unroll
    for (int i = tid; i < 512; i += 256) {
        float4 v = ((const float4*)xr)[i];
        const int j = i * 4;
        *(float4*)&xs[(j >> 7) * 132 + (j & 127)] = v;
    }
    __syncthreads();
    const int n = tid >> 4, ks = tid & 15;
    const float* wv = &Wb[(size_t)n * 2048 + ks * 128];
    const float* xx = &xs[ks * 132];
    float s = 0.f;
#pragma unroll 8
    for (int j = 0; j < 128; j++) s += xx[j] * wv[j];
    s += __shfl_xor(s, 1); s += __shfl_xor(s, 2);
    s += __shfl_xor(s, 4); s += __shfl_xor(s, 8);
    if (ks == 0) beta[(size_t)blockIdx.x * 16 + n] = 1.f / (1.f + __expf(-(s + bb[n])));
}

// ---------------------------------------------------------------- sequential recurrence (R9/R13-proven)
__global__ __launch_bounds__(256)
__attribute__((amdgpu_waves_per_eu(1, 1)))
void recurrence_kernel(
        const float* __restrict__ S0, const float* __restrict__ qall,
        const float* __restrict__ bet, __hip_bfloat16* __restrict__ o) {
    __shared__ __hip_bfloat16 lout[4][64][4];

    const int bh  = blockIdx.x & 31;   // XCD = bh % 8
    const int rb8 = blockIdx.x >> 5;   // 0..7
    const int b = bh >> 4, h = bh & 15;
    const int lane = threadIdx.x & 63;
    const int wave = threadIdx.x >> 6;
    const int r = lane >> 4;
    const int c = lane & 15;
    const int i0 = rb8 * 16 + wave * 4;
    const int i = i0 + r;

    f32x4 S40, S41;
    {
        const float* s0 = &S0[((size_t)(bh * 128 + i)) * 128 + c * 8];
        S40 = *(const f32x4*)s0;
        S41 = *(const f32x4*)(s0 + 4);
    }

    const unsigned SB = 10240 * 4;
    const float* rowb = qall + (size_t)(b * 2048) * 10240 + h * 128;
    const float* qbase = rowb;
    const float* kbase = rowb + 2048;
    const float* vbase = rowb + 4096;
    const float* abase = rowb + 6144;
    const float* gbase = rowb + 8192;
    const float* bbase = bet + (size_t)(b * 2048) * 16 + h;
    char* ob = (char*)(o + ((size_t)(b * 2048) * 16 + h) * 128 + i0);

    unsigned voff_kq = (unsigned)(c * 32);
    unsigned voff_i  = (unsigned)(i * 4);
    unsigned voff_b  = 0;

    f32x4 kA0, kA1, qA0, qA1; float vA, aA, gA, bA;
    f32x4 kB0, kB1, qB0, qB1; float vB, aB, gB, bB;
    f32x4 kC0, kC1, qC0, qC1; float vC, aC, gC, bC;
    f32x4 kD0, kD1, qD0, qD1; float vD, aD, gD, bD;

#define ISSUE(SET)                                                              \
    asm volatile("global_load_dwordx4 %0, %2, %3\n\t"                           \
                 "global_load_dwordx4 %1, %2, %3 offset:16"                     \
                 : "=v"(k##SET##0), "=v"(k##SET##1)                             \
                 : "v"(voff_kq), "s"(kbase));                                   \
    asm volatile("global_load_dwordx4 %0, %2, %3\n\t"                           \
                 "global_load_dwordx4 %1, %2, %3 offset:16"                     \
                 : "=v"(q##SET##0), "=v"(q##SET##1)                             \
                 : "v"(voff_kq), "s"(qbase));                                   \
    asm volatile("global_load_dword %0, %1, %2"                                 \
                 : "=v"(v##SET) : "v"(voff_i), "s"(vbase));                     \
    asm volatile("global_load_dword %0, %1, %2"                                 \
                 : "=v"(a##SET) : "v"(voff_i), "s"(abase));                     \
    asm volatile("global_load_dword %0, %1, %2"                                 \
                 : "=v"(g##SET) : "v"(voff_i), "s"(gbase));                     \
    asm volatile("global_load_dword %0, %1, %2"                                 \
                 : "=v"(b##SET) : "v"(voff_b), "s"(bbase));

#define ADV() { voff_kq += SB; voff_i += SB; voff_b += 64; }

    ISSUE(A); ADV();
    ISSUE(B); ADV();
    ISSUE(C); ADV();
    ISSUE(D); ADV();

#define BODY(SLOT, SET)                                                   \
    {                                                                     \
        asm volatile("s_waitcnt vmcnt(24)");                              \
        asm volatile("" : "+v"(k##SET##0), "+v"(k##SET##1),               \
                          "+v"(q##SET##0), "+v"(q##SET##1),               \
                          "+v"(v##SET), "+v"(a##SET),                     \
                          "+v"(g##SET), "+v"(b##SET));                    \
        f32x4 ps = S40 * k##SET##0;                                       \
        ps = S41 * k##SET##1 + ps;                                        \
        float p = row_sum16((ps[0] + ps[1]) + (ps[2] + ps[3]));           \
        const float coef = b##SET * (v##SET - p);                         \
        S40 = a##SET * S40 + coef * k##SET##0;                            \
        S41 = a##SET * S41 + coef * k##SET##1;                            \
        f32x4 os = S40 * q##SET##0;                                       \
        os = S41 * q##SET##1 + os;                                        \
        float ov = row_sum16((os[0] + os[1]) + (os[2] + os[3]));          \
        if (c == 0) lout[wave][(SLOT)][r] = __float2bfloat16(ov * g##SET);\
        ISSUE(SET);                                                       \
        ADV();                                                            \
    }

    for (int tb = 0; tb < 2048; tb += 64) {
        for (int tt = 0; tt < 64; tt += 4) {
            BODY(tt,     A);
            BODY(tt + 1, B);
            BODY(tt + 2, C);
            BODY(tt + 3, D);
        }
        uint2 pk = *(const uint2*)&lout[wave][lane][0];
        *(uint2*)(ob + (size_t)(tb + lane) * 4096) = pk;
    }
#undef BODY
#undef ADV
#undef ISSUE
}

// ----------------------------------------------------------------
extern "C" void kernel_launch(void* const* d_in, const int* in_sizes, int n_in,
                              void* d_out, int out_size, void* d_ws, size_t ws_size,
                              hipStream_t stream) {
    const float* x  = (const float*)d_in[0];
    const float* S0 = (const float*)d_in[1];
    const float* Wq = (const float*)d_in[2];
    const float* Wk = (const float*)d_in[3];
    const float* Wv = (const float*)d_in[4];
    const float* Wa = (const float*)d_in[5];
    const float* ba = (const float*)d_in[6];
    const float* Wb = (const float*)d_in[7];
    const float* bb = (const float*)d_in[8];
    const float* Wg = (const float*)d_in[9];
    const float* bg = (const float*)d_in[10];
    const float* Wo = (const float*)d_in[11];
    float* out = (float*)d_out;

    const int M = 4096, K = 2048;
    const int NF = 10240;
    const size_t SLACK = 16 * (size_t)NF * 4;

    size_t off = 0;
    auto alloc = [&](size_t bytes) {
        void* p = (char*)d_ws + off;
        off += (bytes + 255) & ~(size_t)255;
        return p;
    };
    short* x_bf  = (short*)alloc((size_t)M * K * 2);     // later reused as o_bf
    short* W_bf  = (short*)alloc((size_t)6 * K * K * 2); // Wq|Wk|Wv|Wa|Wg|Wo contiguous
    float* qall  = (float*)alloc((size_t)M * NF * 4 + SLACK);
    float* betab = (float*)alloc((size_t)M * 16 * 4 + 65536);

    cast_bf16_kernel<<<dim3(M * K / 1024), dim3(256), 0, stream>>>(x, (__hip_bfloat16*)x_bf, M * K);
    cast6_kernel<<<dim3(6 * 4096), dim3(256), 0, stream>>>(Wq, Wk, Wv, Wa, Wg, Wo, (__hip_bfloat16*)W_bf);

    // fused 5-projection GEMM, 256^2 8-phase: [4096,2048] x [10240,2048]^T
    gemm256_fused<<<dim3((M / 256) * (NF / 256)), dim3(512), 0, stream>>>(
        x_bf, W_bf, qall, ba, bg, M, NF, K);

    beta_kernel<<<dim3(M), dim3(256), 0, stream>>>(x, Wb, bb, betab);

    __hip_bfloat16* o_bf = (__hip_bfloat16*)x_bf;
    recurrence_kernel<<<dim3(256), dim3(256), 0, stream>>>(S0, qall, betab, o_bf);

    // out = (o*g) @ Wo^T   (Wo is section 5 of W_bf)
    gemm_nt<<<dim3(M / 128, K / 128), dim3(256), 0, stream>>>(
        (const short*)o_bf, W_bf + (size_t)5 * K * K, out, M, K, K);
}

// Round 17
// 643.688 us; speedup vs baseline: 1.3147x; 1.0117x over previous
//
#include <hip/hip_runtime.h>
#include <hip/hip_bf16.h>

typedef short short8 __attribute__((ext_vector_type(8)));
typedef float f32x4 __attribute__((ext_vector_type(4)));

#define DEV __device__ __forceinline__
#define AS1 __attribute__((address_space(1)))
#define AS3 __attribute__((address_space(3)))

// ---------------------------------------------------------------- async 16B global->LDS
DEV void async_load16(const void* g, void* l) {
    __builtin_amdgcn_global_load_lds((const AS1 unsigned int*)g, (AS3 unsigned int*)l, 16, 0, 0);
}

// ---------------------------------------------------------------- DPP 16-lane sum butterfly
template <int CTRL>
DEV float dpp_add16(float v) {
    int t = __builtin_amdgcn_update_dpp(0, __float_as_int(v), CTRL, 0xf, 0xf, true);
    return v + __int_as_float(t);
}
DEV float row_sum16(float v) {
    v = dpp_add16<0x128>(v);  // row_ror:8
    v = dpp_add16<0x124>(v);  // row_ror:4
    v = dpp_add16<0x122>(v);  // row_ror:2
    v = dpp_add16<0x121>(v);  // row_ror:1
    return v;
}

// ---------------------------------------------------------------- f32 -> bf16 cast (x)
__global__ __launch_bounds__(256) void cast_bf16_kernel(const float* __restrict__ in,
                                                        __hip_bfloat16* __restrict__ out, int n) {
    int i = (blockIdx.x * 256 + threadIdx.x) * 4;
    if (i < n) {
        float4 v = *(const float4*)&in[i];
        out[i + 0] = __float2bfloat16(v.x);
        out[i + 1] = __float2bfloat16(v.y);
        out[i + 2] = __float2bfloat16(v.z);
        out[i + 3] = __float2bfloat16(v.w);
    }
}

// ---------------------------------------------------------------- 6 weight casts in one launch
__global__ __launch_bounds__(256) void cast6_kernel(const float* __restrict__ s0, const float* __restrict__ s1,
                                                    const float* __restrict__ s2, const float* __restrict__ s3,
                                                    const float* __restrict__ s4, const float* __restrict__ s5,
                                                    __hip_bfloat16* __restrict__ dst) {
    const int sec = blockIdx.x >> 12;
    const int loc = blockIdx.x & 4095;
    const float* s = sec == 0 ? s0 : sec == 1 ? s1 : sec == 2 ? s2 : sec == 3 ? s3 : sec == 4 ? s4 : s5;
    const int i = (loc * 256 + threadIdx.x) * 4;
    float4 v = *(const float4*)&s[i];
    __hip_bfloat16* o = dst + (size_t)sec * 4194304 + i;
    o[0] = __float2bfloat16(v.x);
    o[1] = __float2bfloat16(v.y);
    o[2] = __float2bfloat16(v.z);
    o[3] = __float2bfloat16(v.w);
}

// ---------------------------------------------------------------- 256^2 8-phase GEMM (m201 template)
// C = A(M,K) x B(N,K)^T.
// EPI 0: plain f32 store (out-projection).
// EPI 2: fused 5-section epilogue (proj): cols<4096 row-l2norm (q,k) |
//        4096..6143 plain (v) | >=6144 sigmoid+bias (a: bias1, g: bias2).
// Geometry: BM=BN=256, BK=64, 512 thr (8 waves, 2Mx4N), per-wave out 128x64.
// LDS 128 KiB = 16 regions of 16KB; region = (matrix, dbuf, khalf) = [256 rows][32 k].
// Swizzle: kbyte ^= ((row>>1)&3)<<4 (inverse-swizzled global src + swizzled ds_read).
// Each phase stages the region consumed the previous phase; vmcnt(6) once per K-tile.
template <int EPI>
__global__ __launch_bounds__(512, 2) void gemm256_fused(
        const short* __restrict__ A, const short* __restrict__ Bm,
        float* __restrict__ C, const float* __restrict__ bias1,
        const float* __restrict__ bias2, int M, int N, int K) {
    __shared__ short lds_s[65536];  // 131072 B

    const int tid  = threadIdx.x;
    const int lane = tid & 63;
    const int w    = tid >> 6;       // wave 0..7
    const int wave_m = w >> 2;       // 0..1
    const int wave_n = w & 3;        // 0..3
    const int fr  = lane & 15;
    const int fk2 = (lane >> 4) * 16;  // frag k-byte
    const int er  = (lane >> 4) * 4;
    const int ec  = lane & 15;

    const int nbx = M >> 8;          // M/256
    const int wg  = blockIdx.x;
    const int nwg = gridDim.x;
    const int cpx = nwg >> 3;
    const int swz = (wg & 7) * cpx + (wg >> 3);
    const int m0 = (swz & (nbx - 1)) * 256;
    const int n0 = (swz / nbx) * 256;

    const int Kb = K * 2;            // row bytes

    f32x4 acc[8][4] = {};

#define AREG(d, kh) (((d) * 2 + (kh)) << 14)
#define BREG(d, kh) (65536 + (((d) * 2 + (kh)) << 14))

    const int sr0 = w * 32 + (lane >> 2);
    const int sr1 = sr0 + 16;
    const int kbl = (lane & 3) * 16;
    auto STAGE = [&](const short* mat, int rc0, int tkoff, int region) {
        const char* g0 = (const char*)mat + (size_t)(rc0 + sr0) * Kb + tkoff + (kbl ^ (((sr0 >> 1) & 3) << 4));
        const char* g1 = (const char*)mat + (size_t)(rc0 + sr1) * Kb + tkoff + (kbl ^ (((sr1 >> 1) & 3) << 4));
        async_load16(g0, &lds_s[(region + w * 2048) >> 1]);
        async_load16(g1, &lds_s[(region + w * 2048 + 1024) >> 1]);
    };
    auto RDA = [&](int region, int i) -> short8 {
        const int ra = wave_m * 128 + i * 16 + fr;
        return *(const short8*)&lds_s[(region + ra * 64 + (fk2 ^ (((ra >> 1) & 3) << 4))) >> 1];
    };
    auto RDB = [&](int region, int j) -> short8 {
        const int cl = wave_n * 64 + j * 16 + fr;
        return *(const short8*)&lds_s[(region + cl * 64 + (fk2 ^ (((cl >> 1) & 3) << 4))) >> 1];
    };

    STAGE(A,  m0, 0,   AREG(0, 0));  STAGE(A,  m0, 64,  AREG(0, 1));
    STAGE(Bm, n0, 0,   BREG(0, 0));  STAGE(Bm, n0, 64,  BREG(0, 1));
    STAGE(A,  m0, 128, AREG(1, 0));  STAGE(A,  m0, 192, AREG(1, 1));
    STAGE(Bm, n0, 128, BREG(1, 0));  STAGE(Bm, n0, 192, BREG(1, 1));
    asm volatile("s_waitcnt vmcnt(0)" ::: "memory");
    __builtin_amdgcn_s_barrier();
    __builtin_amdgcn_sched_barrier(0);

    short8 af[8], b0, b1;
    const int NT = K >> 6;

#define MFMA8(JA, JB)                                                            \
    __builtin_amdgcn_s_setprio(1);                                               \
    _Pragma("unroll") for (int i = 0; i < 8; i++)                                \
        acc[i][JA] = __builtin_amdgcn_mfma_f32_16x16x32_bf16(af[i], b0, acc[i][JA], 0, 0, 0); \
    _Pragma("unroll") for (int i = 0; i < 8; i++)                                \
        acc[i][JB] = __builtin_amdgcn_mfma_f32_16x16x32_bf16(af[i], b1, acc[i][JB], 0, 0, 0); \
    __builtin_amdgcn_s_setprio(0);

#define ENDPH()                                                                  \
    __builtin_amdgcn_s_barrier();                                                \
    __builtin_amdgcn_sched_barrier(0);

#define KTILE(D, T)                                                              \
    {                                                                            \
        _Pragma("unroll") for (int i = 0; i < 8; i++) af[i] = RDA(AREG(D, 0), i);\
        b0 = RDB(BREG(D, 0), 0); b1 = RDB(BREG(D, 0), 1);                        \
        STAGE(Bm, n0, ((T) + 1) * 128 + 64, BREG(D ^ 1, 1));                     \
        MFMA8(0, 1)                                                              \
        ENDPH()                                                                  \
        b0 = RDB(BREG(D, 0), 2); b1 = RDB(BREG(D, 0), 3);                        \
        STAGE(A, m0, ((T) + 2) * 128, AREG(D, 0));                               \
        MFMA8(2, 3)                                                              \
        ENDPH()                                                                  \
        _Pragma("unroll") for (int i = 0; i < 8; i++) af[i] = RDA(AREG(D, 1), i);\
        b0 = RDB(BREG(D, 1), 0); b1 = RDB(BREG(D, 1), 1);                        \
        STAGE(Bm, n0, ((T) + 2) * 128, BREG(D, 0));                              \
        MFMA8(0, 1)                                                              \
        ENDPH()                                                                  \
        b0 = RDB(BREG(D, 1), 2); b1 = RDB(BREG(D, 1), 3);                        \
        STAGE(A, m0, ((T) + 2) * 128 + 64, AREG(D, 1));                          \
        MFMA8(2, 3)                                                              \
        asm volatile("s_waitcnt vmcnt(6)" ::: "memory");                         \
        ENDPH()                                                                  \
    }

    for (int T = 0; T < NT; T += 2) {
        KTILE(0, T)
        KTILE(1, T + 1)
    }
#undef KTILE
#undef ENDPH
#undef MFMA8

    if constexpr (EPI == 2) {
        const bool isqk = (n0 < 4096);
        if (isqk) {
            __syncthreads();
            float* lsum = (float*)lds_s;   // [4][256]
#pragma unroll
            for (int i = 0; i < 8; i++) {
                float p[4];
#pragma unroll
                for (int r = 0; r < 4; r++) {
                    float s = acc[i][0][r] * acc[i][0][r] + acc[i][1][r] * acc[i][1][r]
                            + acc[i][2][r] * acc[i][2][r] + acc[i][3][r] * acc[i][3][r];
                    p[r] = row_sum16(s);
                }
                if (ec == 0) {
                    const int R = wave_m * 128 + i * 16 + er;
                    lsum[wave_n * 256 + R + 0] = p[0];
                    lsum[wave_n * 256 + R + 1] = p[1];
                    lsum[wave_n * 256 + R + 2] = p[2];
                    lsum[wave_n * 256 + R + 3] = p[3];
                }
            }
            __syncthreads();
            const int h0 = (wave_n & 2);
#pragma unroll
            for (int i = 0; i < 8; i++)
#pragma unroll
                for (int r = 0; r < 4; r++) {
                    const int R = wave_m * 128 + i * 16 + er + r;
                    const float tot = lsum[h0 * 256 + R] + lsum[(h0 + 1) * 256 + R];
                    const float inv = 1.f / fmaxf(sqrtf(tot), 1e-12f);
#pragma unroll
                    for (int j = 0; j < 4; j++) acc[i][j][r] *= inv;
                }
        }
    }

    bool sig = false;
    const float* bp = nullptr;
    if constexpr (EPI == 2) {
        sig = (n0 >= 6144);
        if (sig) bp = (n0 >= 8192) ? (bias2 + (n0 - 8192)) : (bias1 + (n0 - 6144));
    }

#pragma unroll
    for (int i = 0; i < 8; i++) {
        const int gr = m0 + wave_m * 128 + i * 16 + er;
#pragma unroll
        for (int j = 0; j < 4; j++) {
            const int gc = n0 + wave_n * 64 + j * 16 + ec;
            float bia = 0.f;
            if constexpr (EPI == 2) { if (sig) bia = bp[wave_n * 64 + j * 16 + ec]; }
#pragma unroll
            for (int r = 0; r < 4; r++) {
                float v = acc[i][j][r];
                if constexpr (EPI == 2) { if (sig) v = 1.f / (1.f + __expf(-(v + bia))); }
                C[(size_t)(gr + r) * N + gc] = v;
            }
        }
    }
    asm volatile("s_waitcnt vmcnt(0)" ::: "memory");  // drain tail DMAs before endpgm
}

// ---------------------------------------------------------------- beta = sigmoid(x @ Wb^T + bb), f32 exact
__global__ __launch_bounds__(256) void beta_kernel(const float* __restrict__ x,
                                                   const float* __restrict__ Wb,
                                                   const float* __restrict__ bb,
                                                   float* __restrict__ beta) {
    __shared__ float xs[16 * 132];
    const int tid = threadIdx.x;
    const float* xr = &x[(size_t)blockIdx.x * 2048];
#pragma unroll
    for (int i = tid; i < 512; i += 256) {
        float4 v = ((const float4*)xr)[i];
        const int j = i * 4;
        *(float4*)&xs[(j >> 7) * 132 + (j & 127)] = v;
    }
    __syncthreads();
    const int n = tid >> 4, ks = tid & 15;
    const float* wv = &Wb[(size_t)n * 2048 + ks * 128];
    const float* xx = &xs[ks * 132];
    float s = 0.f;
#pragma unroll 8
    for (int j = 0; j < 128; j++) s += xx[j] * wv[j];
    s += __shfl_xor(s, 1); s += __shfl_xor(s, 2);
    s += __shfl_xor(s, 4); s += __shfl_xor(s, 8);
    if (ks == 0) beta[(size_t)blockIdx.x * 16 + n] = 1.f / (1.f + __expf(-(s + bb[n])));
}

// ---------------------------------------------------------------- sequential recurrence (R9/R13-proven)
// 256 blocks x 4 waves, wave = 4 rows x 16 lanes, 8 state f32/lane, XCD-local bh.
// 4-deep asm-volatile register rotation (VGPR 132, spill-free at waves_per_eu(1,1)),
// counted s_waitcnt vmcnt(24) + dataflow register binding of the consumed set ONLY.
__global__ __launch_bounds__(256)
__attribute__((amdgpu_waves_per_eu(1, 1)))
void recurrence_kernel(
        const float* __restrict__ S0, const float* __restrict__ qall,
        const float* __restrict__ bet, __hip_bfloat16* __restrict__ o) {
    __shared__ __hip_bfloat16 lout[4][64][4];

    const int bh  = blockIdx.x & 31;   // XCD = bh % 8
    const int rb8 = blockIdx.x >> 5;   // 0..7
    const int b = bh >> 4, h = bh & 15;
    const int lane = threadIdx.x & 63;
    const int wave = threadIdx.x >> 6;
    const int r = lane >> 4;
    const int c = lane & 15;
    const int i0 = rb8 * 16 + wave * 4;
    const int i = i0 + r;

    f32x4 S40, S41;
    {
        const float* s0 = &S0[((size_t)(bh * 128 + i)) * 128 + c * 8];
        S40 = *(const f32x4*)s0;
        S41 = *(const f32x4*)(s0 + 4);
    }

    const unsigned SB = 10240 * 4;
    const float* rowb = qall + (size_t)(b * 2048) * 10240 + h * 128;
    const float* qbase = rowb;
    const float* kbase = rowb + 2048;
    const float* vbase = rowb + 4096;
    const float* abase = rowb + 6144;
    const float* gbase = rowb + 8192;
    const float* bbase = bet + (size_t)(b * 2048) * 16 + h;
    char* ob = (char*)(o + ((size_t)(b * 2048) * 16 + h) * 128 + i0);

    unsigned voff_kq = (unsigned)(c * 32);
    unsigned voff_i  = (unsigned)(i * 4);
    unsigned voff_b  = 0;

    f32x4 kA0, kA1, qA0, qA1; float vA, aA, gA, bA;
    f32x4 kB0, kB1, qB0, qB1; float vB, aB, gB, bB;
    f32x4 kC0, kC1, qC0, qC1; float vC, aC, gC, bC;
    f32x4 kD0, kD1, qD0, qD1; float vD, aD, gD, bD;

#define ISSUE(SET)                                                              \
    asm volatile("global_load_dwordx4 %0, %2, %3\n\t"                           \
                 "global_load_dwordx4 %1, %2, %3 offset:16"                     \
                 : "=v"(k##SET##0), "=v"(k##SET##1)                             \
                 : "v"(voff_kq), "s"(kbase));                                   \
    asm volatile("global_load_dwordx4 %0, %2, %3\n\t"                           \
                 "global_load_dwordx4 %1, %2, %3 offset:16"                     \
                 : "=v"(q##SET##0), "=v"(q##SET##1)                             \
                 : "v"(voff_kq), "s"(qbase));                                   \
    asm volatile("global_load_dword %0, %1, %2"                                 \
                 : "=v"(v##SET) : "v"(voff_i), "s"(vbase));                     \
    asm volatile("global_load_dword %0, %1, %2"                                 \
                 : "=v"(a##SET) : "v"(voff_i), "s"(abase));                     \
    asm volatile("global_load_dword %0, %1, %2"                                 \
                 : "=v"(g##SET) : "v"(voff_i), "s"(gbase));                     \
    asm volatile("global_load_dword %0, %1, %2"                                 \
                 : "=v"(b##SET) : "v"(voff_b), "s"(bbase));

#define ADV() { voff_kq += SB; voff_i += SB; voff_b += 64; }

    ISSUE(A); ADV();
    ISSUE(B); ADV();
    ISSUE(C); ADV();
    ISSUE(D); ADV();

#define BODY(SLOT, SET)                                                   \
    {                                                                     \
        asm volatile("s_waitcnt vmcnt(24)");                              \
        asm volatile("" : "+v"(k##SET##0), "+v"(k##SET##1),               \
                          "+v"(q##SET##0), "+v"(q##SET##1),               \
                          "+v"(v##SET), "+v"(a##SET),                     \
                          "+v"(g##SET), "+v"(b##SET));                    \
        f32x4 ps = S40 * k##SET##0;                                       \
        ps = S41 * k##SET##1 + ps;                                        \
        float p = row_sum16((ps[0] + ps[1]) + (ps[2] + ps[3]));           \
        const float coef = b##SET * (v##SET - p);                         \
        S40 = a##SET * S40 + coef * k##SET##0;                            \
        S41 = a##SET * S41 + coef * k##SET##1;                            \
        f32x4 os = S40 * q##SET##0;                                       \
        os = S41 * q##SET##1 + os;                                        \
        float ov = row_sum16((os[0] + os[1]) + (os[2] + os[3]));          \
        if (c == 0) lout[wave][(SLOT)][r] = __float2bfloat16(ov * g##SET);\
        ISSUE(SET);                                                       \
        ADV();                                                            \
    }

    for (int tb = 0; tb < 2048; tb += 64) {
        for (int tt = 0; tt < 64; tt += 4) {
            BODY(tt,     A);
            BODY(tt + 1, B);
            BODY(tt + 2, C);
            BODY(tt + 3, D);
        }
        uint2 pk = *(const uint2*)&lout[wave][lane][0];
        *(uint2*)(ob + (size_t)(tb + lane) * 4096) = pk;
    }
#undef BODY
#undef ADV
#undef ISSUE
}

// ----------------------------------------------------------------
extern "C" void kernel_launch(void* const* d_in, const int* in_sizes, int n_in,
                              void* d_out, int out_size, void* d_ws, size_t ws_size,
                              hipStream_t stream) {
    const float* x  = (const float*)d_in[0];
    const float* S0 = (const float*)d_in[1];
    const float* Wq = (const float*)d_in[2];
    const float* Wk = (const float*)d_in[3];
    const float* Wv = (const float*)d_in[4];
    const float* Wa = (const float*)d_in[5];
    const float* ba = (const float*)d_in[6];
    const float* Wb = (const float*)d_in[7];
    const float* bb = (const float*)d_in[8];
    const float* Wg = (const float*)d_in[9];
    const float* bg = (const float*)d_in[10];
    const float* Wo = (const float*)d_in[11];
    float* out = (float*)d_out;

    const int M = 4096, K = 2048;
    const int NF = 10240;
    const size_t SLACK = 16 * (size_t)NF * 4;

    size_t off = 0;
    auto alloc = [&](size_t bytes) {
        void* p = (char*)d_ws + off;
        off += (bytes + 255) & ~(size_t)255;
        return p;
    };
    short* x_bf  = (short*)alloc((size_t)M * K * 2);     // later reused as o_bf
    short* W_bf  = (short*)alloc((size_t)6 * K * K * 2); // Wq|Wk|Wv|Wa|Wg|Wo contiguous
    float* qall  = (float*)alloc((size_t)M * NF * 4 + SLACK);
    float* betab = (float*)alloc((size_t)M * 16 * 4 + 65536);

    cast_bf16_kernel<<<dim3(M * K / 1024), dim3(256), 0, stream>>>(x, (__hip_bfloat16*)x_bf, M * K);
    cast6_kernel<<<dim3(6 * 4096), dim3(256), 0, stream>>>(Wq, Wk, Wv, Wa, Wg, Wo, (__hip_bfloat16*)W_bf);

    // fused 5-projection GEMM, 256^2 8-phase: [4096,2048] x [10240,2048]^T
    gemm256_fused<2><<<dim3((M / 256) * (NF / 256)), dim3(512), 0, stream>>>(
        x_bf, W_bf, qall, ba, bg, M, NF, K);

    beta_kernel<<<dim3(M), dim3(256), 0, stream>>>(x, Wb, bb, betab);

    __hip_bfloat16* o_bf = (__hip_bfloat16*)x_bf;
    recurrence_kernel<<<dim3(256), dim3(256), 0, stream>>>(S0, qall, betab, o_bf);

    // out = (o*g) @ Wo^T, 256^2 8-phase (N=2048 -> 128 wgs, %8==0)
    gemm256_fused<0><<<dim3((M / 256) * (K / 256)), dim3(512), 0, stream>>>(
        (const short*)o_bf, W_bf + (size_t)5 * K * K, out, nullptr, nullptr, M, K, K);
}